// Round 14
// baseline (170.172 us; speedup 1.0000x reference)
//
#include <hip/hip_runtime.h>
#include <hip/hip_bf16.h>
#include <math.h>

#define B 4
#define C 256
#define G 8
#define N 4096
#define EPSV 1e-5f
#define QSCALE 0.0901684400f   // (1/16) * log2(e): softmax runs in exp2 domain
#define THR2 11.5416f          // 8 * log2(e)

typedef __attribute__((ext_vector_type(8))) short short8;
typedef __attribute__((ext_vector_type(16))) float f32x16;
typedef unsigned short ushort_t;
typedef unsigned int uint_t;

// ---- bf16 helpers (bit-level, RNE) ----
__device__ __forceinline__ ushort_t f2bf(float f) {
    union { float f; uint_t u; } c; c.f = f;
    uint_t u = c.u;
    uint_t r = (u + 0x7FFFu + ((u >> 16) & 1u)) >> 16;
    return (ushort_t)r;
}
__device__ __forceinline__ float bf2f(ushort_t h) {
    union { uint_t u; float f; } c; c.u = ((uint_t)h) << 16;
    return c.f;
}
__device__ __forceinline__ uint_t pack2(float a, float b) {
    return (uint_t)f2bf(a) | ((uint_t)f2bf(b) << 16);
}
__device__ __forceinline__ uint_t cvtpk_bf16(float lo, float hi) {
    uint_t r;
    asm("v_cvt_pk_bf16_f32 %0, %1, %2" : "=v"(r) : "v"(lo), "v"(hi));
    return r;
}
__device__ __forceinline__ float fexp2(float x) {
    return __builtin_amdgcn_exp2f(x);   // bare v_exp_f32 (2^x)
}
__device__ __forceinline__ void gl_lds16(const void* g, void* l) {
    __builtin_amdgcn_global_load_lds(
        (const __attribute__((address_space(1))) void*)g,
        (__attribute__((address_space(3))) void*)l, 16, 0, 0);
}

// ---------------- K1: groupnorm partial sums ++ weight conversion ----------------
__global__ __launch_bounds__(256) void gn_wconv(const float* __restrict__ x,
        float* __restrict__ partials, const float* __restrict__ wq,
        const float* __restrict__ wp, ushort_t* __restrict__ wbf) {
    int blk = blockIdx.x;
    if (blk < 256) {
        int bg = blk >> 3;
        int part = blk & 7;
        const float4* xp4 = (const float4*)(x + (size_t)bg * (32 * N) + (size_t)part * (32 * N / 8));
        float s = 0.f, ss = 0.f;
        for (int i = threadIdx.x; i < 4096; i += 256) {
            float4 v = xp4[i];
            s  += v.x + v.y + v.z + v.w;
            ss += v.x*v.x + v.y*v.y + v.z*v.z + v.w*v.w;
        }
        __shared__ float rs[256], rss[256];
        rs[threadIdx.x] = s; rss[threadIdx.x] = ss;
        __syncthreads();
        for (int off = 128; off > 0; off >>= 1) {
            if (threadIdx.x < off) {
                rs[threadIdx.x]  += rs[threadIdx.x + off];
                rss[threadIdx.x] += rss[threadIdx.x + off];
            }
            __syncthreads();
        }
        if (threadIdx.x == 0) {
            partials[(bg*8 + part)*2]     = rs[0];
            partials[(bg*8 + part)*2 + 1] = rss[0];
        }
    } else {
        int idx = (blk - 256)*256 + threadIdx.x;
        #pragma unroll
        for (int p = 0; p < 4; p++) {
            int id = idx + p*16384;
            float4 v = (id < 49152) ? ((const float4*)wq)[id] : ((const float4*)wp)[id - 49152];
            uint2 pk; pk.x = pack2(v.x, v.y); pk.y = pack2(v.z, v.w);
            *(uint2*)&wbf[(size_t)id*4] = pk;
        }
    }
}

// ---------------- K2: fused groupnorm-finalize + groupnorm + QKV GEMM ----------------
__global__ __launch_bounds__(256) void qkv_fused(const float* __restrict__ x,
        const ushort_t* __restrict__ wbf, const float* __restrict__ gamma,
        const float* __restrict__ beta, const float* __restrict__ partials,
        const float* __restrict__ bias,
        ushort_t* __restrict__ qbf, ushort_t* __restrict__ kimg, ushort_t* __restrict__ vimg) {
    int b = blockIdx.z, o0 = blockIdx.y*128, n0 = blockIdx.x*128;
    int tid = threadIdx.x;
    int w = tid>>6, l = tid&63, l31 = l&31, lh = l>>5;
    int cg = tid >> 5;
    int nq = tid & 31;
    __shared__ short Ws[2][8192];
    __shared__ short Hs[2][8192];
    __shared__ float sst[16];

    if (tid < 8) {
        float s = 0.f, ss = 0.f;
        #pragma unroll
        for (int p = 0; p < 8; p++) {
            s  += partials[((b*8 + tid)*8 + p)*2];
            ss += partials[((b*8 + tid)*8 + p)*2 + 1];
        }
        const float inv = 1.f / 131072.f;
        float mu = s * inv;
        float var = fmaxf(ss * inv - mu*mu, 0.f);
        sst[tid*2]     = mu;
        sst[tid*2 + 1] = rsqrtf(var + EPSV);
    }
    __syncthreads();

    const ushort_t* wb = wbf + (size_t)o0*256;

    auto stageW = [&](int bb, int c0) {
        #pragma unroll
        for (int q = 0; q < 4; q++) {
            int u0 = (q*4 + w)*64;
            int u  = u0 + l;
            int row = u & 127, ch = u >> 7;
            gl_lds16(wb + (size_t)row*256 + c0 + ch*8, &Ws[bb][u0*8]);
        }
    };
    auto loadX = [&](int c0, float4* xv) {
        const float* xb = x + ((size_t)b*C + c0 + cg*8)*N + n0 + nq*4;
        #pragma unroll
        for (int e = 0; e < 8; e++)
            xv[e] = *(const float4*)(xb + (size_t)e*N);
    };
    auto writeH = [&](int bb, int c0, const float4* xv) {
        int cbase = c0 + cg*8;
        int g = cbase >> 5;
        float mu = sst[g*2], rs = sst[g*2+1];
        float ga[8], be[8];
        #pragma unroll
        for (int e = 0; e < 8; e++) {
            float gm = gamma[cbase+e];
            ga[e] = gm*rs;
            be[e] = beta[cbase+e] - mu*ga[e];
        }
        #pragma unroll
        for (int j = 0; j < 4; j++) {
            float h[8];
            #pragma unroll
            for (int e = 0; e < 8; e++) {
                float vx = (j==0) ? xv[e].x : (j==1) ? xv[e].y : (j==2) ? xv[e].z : xv[e].w;
                h[e] = vx*ga[e] + be[e];
            }
            uint4 pk;
            pk.x = pack2(h[0], h[1]);
            pk.y = pack2(h[2], h[3]);
            pk.z = pack2(h[4], h[5]);
            pk.w = pack2(h[6], h[7]);
            *(uint4*)&Hs[bb][(size_t)(cg*128 + nq*4 + j)*8] = pk;
        }
    };

    f32x16 acc[4];
    #pragma unroll
    for (int nf = 0; nf < 4; nf++)
        #pragma unroll
        for (int r = 0; r < 16; r++) acc[nf][r] = 0.f;

    float4 xv[8];
    loadX(0, xv);
    stageW(0, 0);
    writeH(0, 0, xv);
    __syncthreads();

    for (int t = 0; t < 4; t++) {
        int bb = t & 1;
        if (t < 3) { stageW(bb^1, (t+1)*64); loadX((t+1)*64, xv); }
        short8 af[4];
        #pragma unroll
        for (int s = 0; s < 4; s++)
            af[s] = *(const short8*)&Ws[bb][((2*s+lh)*128 + w*32 + l31)*8];
        #pragma unroll
        for (int nf = 0; nf < 4; nf++) {
            #pragma unroll
            for (int s = 0; s < 4; s++) {
                short8 hf = *(const short8*)&Hs[bb][((2*s+lh)*128 + nf*32 + l31)*8];
                acc[nf] = __builtin_amdgcn_mfma_f32_32x32x16_bf16(af[s], hf, acc[nf], 0, 0, 0);
            }
        }
        if (t < 3) writeH(bb^1, (t+1)*64, xv);
        __syncthreads();
    }

    int ow = o0 + w*32;
    float bv[16];
    #pragma unroll
    for (int r = 0; r < 16; r++) bv[r] = bias[ow + (r&3) + 8*(r>>2) + 4*lh];

    if (ow < 256) {
        #pragma unroll
        for (int nf = 0; nf < 4; nf++) {
            int n = n0 + nf*32 + l31;
            ushort_t* row = qbf + ((size_t)(b*N + n))*256 + ow;
            #pragma unroll
            for (int rp = 0; rp < 8; rp++) {
                int r0 = rp*2;
                int cl = (r0&3) + 8*(r0>>2) + 4*lh;
                uint_t wd = cvtpk_bf16((acc[nf][r0]+bv[r0])*QSCALE, (acc[nf][r0+1]+bv[r0+1])*QSCALE);
                *(uint_t*)(row + cl) = wd;
            }
        }
    } else if (ow < 512) {
        int cb = ow - 256;
        #pragma unroll
        for (int nf = 0; nf < 4; nf++) {
            int n = n0 + nf*32 + l31;
            ushort_t* tbase = kimg + (size_t)b*1048576 + (size_t)(n>>5)*8192
                            + (size_t)l31*8 + 4*lh;
            #pragma unroll
            for (int g = 0; g < 4; g++) {
                uint2 pk;
                pk.x = pack2(acc[nf][g*4+0]+bv[g*4+0], acc[nf][g*4+1]+bv[g*4+1]);
                pk.y = pack2(acc[nf][g*4+2]+bv[g*4+2], acc[nf][g*4+3]+bv[g*4+3]);
                *(uint2*)(tbase + (size_t)((cb>>3)+g)*256) = pk;
            }
        }
    } else {
        int cb = ow - 512;
        #pragma unroll
        for (int nf = 0; nf < 4; nf++) {
            int n = n0 + nf*32 + l31;
            ushort_t* tbase = vimg + (size_t)b*1048576 + (size_t)(n>>5)*8192
                            + (size_t)(l31>>3)*2048 + (l31&7);
            #pragma unroll
            for (int r = 0; r < 16; r++) {
                int cl = (r&3) + 8*(r>>2) + 4*lh;
                tbase[(size_t)(cb+cl)*8] = f2bf(acc[nf][r] + bv[r]);
            }
        }
    }
}

// ---------------- K3: MFMA flash attention, kv4, 2 blocks/CU, QK-ahead pipeline ----------------
// K(j) consumed in iter j-1, V(j) in iter j  =>  2 K-slots + 3 V-slots = 80 KB
// (exactly 2 blocks/CU). Single S-accumulator chain per buffer (stA/stB), p in-place.
__global__ __launch_bounds__(256, 2) void attn_mfma(const ushort_t* __restrict__ qbf,
        const ushort_t* __restrict__ kimg, const ushort_t* __restrict__ vimg,
        ushort_t* __restrict__ part, float* __restrict__ ml) {
    int f = blockIdx.x;
    int comb = f & 15;
    int qt  = f >> 4;
    int b   = comb >> 2;
    int kvq = comb & 3;
    constexpr int NT = 32;
    int w = threadIdx.x >> 6;
    int l = threadIdx.x & 63;
    int l31 = l & 31, lh = l >> 5;

    __shared__ short Kl[2][8192];   // K(j) in Kl[j&1]
    __shared__ short Vl[3][8192];   // V(j) in Vl[j%3]

    int qbase = qt*128 + w*32;
    short8 qf[16];
    {
        const ushort_t* qrow = qbf + ((size_t)(b*N + qbase + l31))*256;
        #pragma unroll
        for (int s = 0; s < 16; s++)
            qf[s] = *(const short8*)(qrow + s*16 + lh*8);
    }

    f32x16 ot[8];
    #pragma unroll
    for (int mc = 0; mc < 8; mc++)
        #pragma unroll
        for (int r = 0; r < 16; r++) ot[mc][r] = 0.f;
    float m = -INFINITY, lsum = 0.f;

    const char* kbase = (const char*)kimg + (size_t)b*2097152;
    const char* vbase = (const char*)vimg + (size_t)b*2097152;

    auto stage = [&](int j) {
        int tile = kvq*32 + j;
        const char* kt = kbase + (size_t)tile*16384;
        const char* vt = vbase + (size_t)tile*16384;
        short* kd = &Kl[j & 1][0];
        short* vd = &Vl[j % 3][0];
        #pragma unroll
        for (int q = 0; q < 4; q++) {
            int u0 = (w*4 + q)*64;
            gl_lds16(kt + (u0 + l)*16, kd + u0*8);
            gl_lds16(vt + (u0 + l)*16, vd + u0*8);
        }
    };

    // single-chain QK: row 2j+lh pairs with qf[j]
    auto qk_issue = [&](int j, f32x16& s) {
        #pragma unroll
        for (int r = 0; r < 16; r++) s[r] = 0.f;
        const short* kb_ = &Kl[j & 1][0];
        __builtin_amdgcn_s_setprio(1);
        #pragma unroll
        for (int s2 = 0; s2 < 16; s2++) {
            short8 ka = *(const short8*)(kb_ + ((size_t)((2*s2 + lh)*32 + l31))*8);
            s = __builtin_amdgcn_mfma_f32_32x32x16_bf16(ka, qf[s2], s, 0, 0, 0);
        }
        __builtin_amdgcn_s_setprio(0);
    };

    // body(t): cur = scores of tile t (issued last iter); issues QK(t+1) into nxt.
    auto body = [&](int t, f32x16& cur, f32x16& nxt) {
        __syncthreads();                         // stage(t+1) complete (issued ~1 iter ago)
        if (t+1 < NT) qk_issue(t+1, nxt);        // fills matrix pipe for this iter
        if (t+2 < NT) stage(t+2);                // K->Kl[t&1] (dead), V->Vl[(t+2)%3] (dead)

        // ---- softmax(t) on cur, in-place p ----
        float a0 = fmaxf(cur[0], cur[1]),  a1 = fmaxf(cur[2], cur[3]);
        float a2 = fmaxf(cur[4], cur[5]),  a3 = fmaxf(cur[6], cur[7]);
        float a4 = fmaxf(cur[8], cur[9]),  a5 = fmaxf(cur[10], cur[11]);
        float a6 = fmaxf(cur[12], cur[13]), a7 = fmaxf(cur[14], cur[15]);
        float b0 = fmaxf(a0, a1), b1 = fmaxf(a2, a3), b2 = fmaxf(a4, a5), b3 = fmaxf(a6, a7);
        float pmax = fmaxf(fmaxf(b0, b1), fmaxf(b2, b3));
        pmax = fmaxf(pmax, __shfl_xor(pmax, 32));
        if (!__all(pmax <= m + THR2)) {
            float mn = fmaxf(m, pmax);
            float fac = fexp2(m - mn);
            m = mn;
            lsum *= fac;
            #pragma unroll
            for (int mc = 0; mc < 8; mc++)
                #pragma unroll
                for (int r = 0; r < 16; r++) ot[mc][r] *= fac;
        }
        #pragma unroll
        for (int r = 0; r < 16; r++) cur[r] = fexp2(cur[r] - m);   // cur := p
        float s0_ = (cur[0]+cur[1]) + (cur[2]+cur[3]);
        float s1_ = (cur[4]+cur[5]) + (cur[6]+cur[7]);
        float s2_ = (cur[8]+cur[9]) + (cur[10]+cur[11]);
        float s3_ = (cur[12]+cur[13]) + (cur[14]+cur[15]);
        float ls = (s0_+s1_) + (s2_+s3_);
        ls += __shfl_xor(ls, 32);
        lsum += ls;

        short8 pf0, pf1;
        {
            uint_t x0 = cvtpk_bf16(cur[0], cur[1]);
            uint_t y0 = cvtpk_bf16(cur[4], cur[5]);
            uint_t x1 = cvtpk_bf16(cur[2], cur[3]);
            uint_t y1 = cvtpk_bf16(cur[6], cur[7]);
            auto r0 = __builtin_amdgcn_permlane32_swap(x0, y0, false, false);
            auto r1 = __builtin_amdgcn_permlane32_swap(x1, y1, false, false);
            union { uint_t u[4]; short8 s8; } u_;
            u_.u[0] = r0[0]; u_.u[1] = r1[0]; u_.u[2] = r0[1]; u_.u[3] = r1[1];
            pf0 = u_.s8;
            uint_t x2 = cvtpk_bf16(cur[8],  cur[9]);
            uint_t y2 = cvtpk_bf16(cur[12], cur[13]);
            uint_t x3 = cvtpk_bf16(cur[10], cur[11]);
            uint_t y3 = cvtpk_bf16(cur[14], cur[15]);
            auto r2 = __builtin_amdgcn_permlane32_swap(x2, y2, false, false);
            auto r3 = __builtin_amdgcn_permlane32_swap(x3, y3, false, false);
            union { uint_t u[4]; short8 s8; } u2_;
            u2_.u[0] = r2[0]; u2_.u[1] = r3[0]; u2_.u[2] = r2[1]; u2_.u[3] = r3[1];
            pf1 = u2_.s8;
        }

        // ---- PV(t) ----
        const short* vb_ = &Vl[t % 3][0];
        __builtin_amdgcn_s_setprio(1);
        #pragma unroll
        for (int mc = 0; mc < 8; mc++) {
            short8 v0 = *(const short8*)(vb_ + ((size_t)((lh)*256   + mc*32 + l31))*8);
            short8 v1 = *(const short8*)(vb_ + ((size_t)((2+lh)*256 + mc*32 + l31))*8);
            ot[mc] = __builtin_amdgcn_mfma_f32_32x32x16_bf16(v0, pf0, ot[mc], 0, 0, 0);
            ot[mc] = __builtin_amdgcn_mfma_f32_32x32x16_bf16(v1, pf1, ot[mc], 0, 0, 0);
        }
        __builtin_amdgcn_s_setprio(0);
    };

    f32x16 stA, stB;

    // prologue: stage(0) -> QK(0) -> stage(1)
    stage(0);
    __syncthreads();
    qk_issue(0, stA);
    stage(1);

    for (int t = 0; t < NT; t += 2) {
        body(t,   stA, stB);
        body(t+1, stB, stA);
    }

    float invl = 1.f / lsum;
    ushort_t* pbase = part + (size_t)kvq*4194304 + ((size_t)(b*N + qbase + l31))*256;
    #pragma unroll
    for (int mc = 0; mc < 8; mc++)
        #pragma unroll
        for (int rp = 0; rp < 8; rp++) {
            int r0 = rp*2;
            uint_t wd = cvtpk_bf16(ot[mc][r0]*invl, ot[mc][r0+1]*invl);
            int c0 = (r0 & 3) + 8*(r0 >> 2) + 4*lh + 32*mc;
            *(uint_t*)(pbase + c0) = wd;
        }
    if (l < 32) {
        size_t row = (size_t)kvq*16384 + b*4096 + qbase + l;
        ml[row*2]     = m;
        ml[row*2 + 1] = lsum;
    }
}

// ---------------- K4: proj GEMM + inline 4-way merge + bias + residual ----------------
__global__ __launch_bounds__(256) void proj_merge(const ushort_t* __restrict__ part,
        const float* __restrict__ ml, const ushort_t* __restrict__ wpbf,
        const float* __restrict__ bp, const float* __restrict__ x, float* __restrict__ out) {
    int b = blockIdx.z, o0 = blockIdx.y*128, n0 = blockIdx.x*64;
    int tid = threadIdx.x;
    int w = tid>>6, l = tid&63, l31 = l&31, lh = l>>5;
    __shared__ short Ws[2][8192];
    __shared__ short Hs[2][4096];

    const ushort_t* wb = wpbf + (size_t)o0*256;

    int srow = tid & 63;
    int ch0  = tid >> 6;
    size_t rowbase = ((size_t)(b*4096 + n0 + srow))*256;
    float wv[4];
    {
        float mv[4], lv[4];
        #pragma unroll
        for (int i = 0; i < 4; i++) {
            size_t rr = (size_t)i*16384 + b*4096 + n0 + srow;
            mv[i] = ml[rr*2];
            lv[i] = ml[rr*2 + 1];
        }
        float M = fmaxf(fmaxf(mv[0], mv[1]), fmaxf(mv[2], mv[3]));
        float wsum = 0.f;
        #pragma unroll
        for (int i = 0; i < 4; i++) { wv[i] = fexp2(mv[i] - M)*lv[i]; wsum += wv[i]; }
        float inv = 1.f / wsum;
        #pragma unroll
        for (int i = 0; i < 4; i++) wv[i] *= inv;
    }

    auto stageW = [&](int bb, int c0) {
        #pragma unroll
        for (int q = 0; q < 4; q++) {
            int u0 = (q*4 + w)*64;
            int u  = u0 + l;
            int row = u & 127, ch = u >> 7;
            gl_lds16(wb + (size_t)row*256 + c0 + ch*8, &Ws[bb][u0*8]);
        }
    };
    short8 hA[4], hB[4];
    auto Hload = [&](int c0) {
        #pragma unroll
        for (int i = 0; i < 4; i++) {
            const ushort_t* pp = part + (size_t)i*4194304 + rowbase + c0;
            hA[i] = *(const short8*)(pp + ch0*8);
            hB[i] = *(const short8*)(pp + (ch0+4)*8);
        }
    };
    auto Hwrite = [&](int bb) {
        float oA[8], oB[8];
        #pragma unroll
        for (int e = 0; e < 8; e++) { oA[e] = 0.f; oB[e] = 0.f; }
        #pragma unroll
        for (int i = 0; i < 4; i++) {
            float wi = wv[i];
            #pragma unroll
            for (int e = 0; e < 8; e++) {
                oA[e] += wi*bf2f((ushort_t)hA[i][e]);
                oB[e] += wi*bf2f((ushort_t)hB[i][e]);
            }
        }
        uint4 pkA, pkB;
        pkA.x = pack2(oA[0], oA[1]); pkA.y = pack2(oA[2], oA[3]);
        pkA.z = pack2(oA[4], oA[5]); pkA.w = pack2(oA[6], oA[7]);
        pkB.x = pack2(oB[0], oB[1]); pkB.y = pack2(oB[2], oB[3]);
        pkB.z = pack2(oB[4], oB[5]); pkB.w = pack2(oB[6], oB[7]);
        *(uint4*)&Hs[bb][(size_t)(ch0*64 + srow)*8]     = pkA;
        *(uint4*)&Hs[bb][(size_t)((ch0+4)*64 + srow)*8] = pkB;
    };

    f32x16 acc[2];
    #pragma unroll
    for (int nf = 0; nf < 2; nf++)
        #pragma unroll
        for (int r = 0; r < 16; r++) acc[nf][r] = 0.f;

    stageW(0, 0);
    Hload(0);
    Hwrite(0);
    __syncthreads();
    for (int t = 0; t < 4; t++) {
        int bb = t & 1;
        if (t < 3) { stageW(bb^1, (t+1)*64); Hload((t+1)*64); }
        short8 af[4];
        #pragma unroll
        for (int s = 0; s < 4; s++)
            af[s] = *(const short8*)&Ws[bb][((2*s+lh)*128 + w*32 + l31)*8];
        #pragma unroll
        for (int nf = 0; nf < 2; nf++) {
            #pragma unroll
            for (int s = 0; s < 4; s++) {
                short8 hf = *(const short8*)&Hs[bb][((2*s+lh)*64 + nf*32 + l31)*8];
                acc[nf] = __builtin_amdgcn_mfma_f32_32x32x16_bf16(af[s], hf, acc[nf], 0, 0, 0);
            }
        }
        if (t < 3) Hwrite(bb^1);
        __syncthreads();
    }

    int cw = o0 + w*32;
    float bv[16];
    #pragma unroll
    for (int r = 0; r < 16; r++) bv[r] = bp[cw + (r&3) + 8*(r>>2) + 4*lh];

    #pragma unroll
    for (int nf = 0; nf < 2; nf++) {
        int n = n0 + nf*32 + l31;
        #pragma unroll
        for (int r = 0; r < 16; r++) {
            int cl = (r&3) + 8*(r>>2) + 4*lh;
            size_t a = ((size_t)b*C + cw + cl)*N + n;
            out[a] = acc[nf][r] + bv[r] + x[a];
        }
    }
}

extern "C" void kernel_launch(void* const* d_in, const int* in_sizes, int n_in,
                              void* d_out, int out_size, void* d_ws, size_t ws_size,
                              hipStream_t stream) {
    const float* x      = (const float*)d_in[0];
    const float* gamma  = (const float*)d_in[1];
    const float* beta   = (const float*)d_in[2];
    const float* w_qkv  = (const float*)d_in[3];
    const float* b_qkv  = (const float*)d_in[4];
    const float* w_proj = (const float*)d_in[5];
    const float* b_proj = (const float*)d_in[6];
    float* out = (float*)d_out;
    char* wsb  = (char*)d_ws;

    const size_t MB = 1048576;
    ushort_t* qbf  = (ushort_t*)(wsb);                       // 8 MB
    ushort_t* kimg = (ushort_t*)(wsb + 8*MB);                // 8 MB
    ushort_t* vimg = (ushort_t*)(wsb + 16*MB);               // 8 MB
    ushort_t* part = (ushort_t*)(wsb + 24*MB);               // 32 MB (4 quarters)
    float*    ml   = (float*)  (wsb + 56*MB);                // 512 KB
    float* partials = (float*) (wsb + 56*MB + 524288);       // 2 KB
    ushort_t* wbf  = (ushort_t*)(wsb + 56*MB + 528384);      // 512 KB

    gn_wconv<<<dim3(320), dim3(256), 0, stream>>>(x, partials, w_qkv, w_proj, wbf);
    qkv_fused<<<dim3(32, 6, 4), dim3(256), 0, stream>>>(x, wbf, gamma, beta, partials, b_qkv, qbf, kimg, vimg);
    attn_mfma<<<dim3(512), dim3(256), 0, stream>>>(qbf, kimg, vimg, part, ml);
    proj_merge<<<dim3(64, 2, 4), dim3(256), 0, stream>>>(part, ml, wbf + 196608, b_proj, x, out);
}

// Round 16
// 137.681 us; speedup vs baseline: 1.2360x; 1.2360x over previous
//
#include <hip/hip_runtime.h>
#include <hip/hip_bf16.h>
#include <math.h>

#define B 4
#define C 256
#define G 8
#define N 4096
#define EPSV 1e-5f
#define QSCALE 0.0901684400f   // (1/16) * log2(e): softmax runs in exp2 domain
#define THR2 11.5416f          // 8 * log2(e)

typedef __attribute__((ext_vector_type(8))) short short8;
typedef __attribute__((ext_vector_type(16))) float f32x16;
typedef unsigned short ushort_t;
typedef unsigned int uint_t;

// ---- bf16 helpers (bit-level, RNE) ----
__device__ __forceinline__ ushort_t f2bf(float f) {
    union { float f; uint_t u; } c; c.f = f;
    uint_t u = c.u;
    uint_t r = (u + 0x7FFFu + ((u >> 16) & 1u)) >> 16;
    return (ushort_t)r;
}
__device__ __forceinline__ float bf2f(ushort_t h) {
    union { uint_t u; float f; } c; c.u = ((uint_t)h) << 16;
    return c.f;
}
__device__ __forceinline__ uint_t pack2(float a, float b) {
    return (uint_t)f2bf(a) | ((uint_t)f2bf(b) << 16);
}
__device__ __forceinline__ uint_t cvtpk_bf16(float lo, float hi) {
    uint_t r;
    asm("v_cvt_pk_bf16_f32 %0, %1, %2" : "=v"(r) : "v"(lo), "v"(hi));
    return r;
}
__device__ __forceinline__ float fexp2(float x) {
    return __builtin_amdgcn_exp2f(x);   // bare v_exp_f32 (2^x)
}
__device__ __forceinline__ void gl_lds16(const void* g, void* l) {
    __builtin_amdgcn_global_load_lds(
        (const __attribute__((address_space(1))) void*)g,
        (__attribute__((address_space(3))) void*)l, 16, 0, 0);
}

// ---------------- K1: groupnorm partial sums ++ weight conversion ----------------
__global__ __launch_bounds__(256) void gn_wconv(const float* __restrict__ x,
        float* __restrict__ partials, const float* __restrict__ wq,
        const float* __restrict__ wp, ushort_t* __restrict__ wbf) {
    int blk = blockIdx.x;
    if (blk < 256) {
        int bg = blk >> 3;
        int part = blk & 7;
        const float4* xp4 = (const float4*)(x + (size_t)bg * (32 * N) + (size_t)part * (32 * N / 8));
        float s = 0.f, ss = 0.f;
        for (int i = threadIdx.x; i < 4096; i += 256) {
            float4 v = xp4[i];
            s  += v.x + v.y + v.z + v.w;
            ss += v.x*v.x + v.y*v.y + v.z*v.z + v.w*v.w;
        }
        __shared__ float rs[256], rss[256];
        rs[threadIdx.x] = s; rss[threadIdx.x] = ss;
        __syncthreads();
        for (int off = 128; off > 0; off >>= 1) {
            if (threadIdx.x < off) {
                rs[threadIdx.x]  += rs[threadIdx.x + off];
                rss[threadIdx.x] += rss[threadIdx.x + off];
            }
            __syncthreads();
        }
        if (threadIdx.x == 0) {
            partials[(bg*8 + part)*2]     = rs[0];
            partials[(bg*8 + part)*2 + 1] = rss[0];
        }
    } else {
        int idx = (blk - 256)*256 + threadIdx.x;
        #pragma unroll
        for (int p = 0; p < 4; p++) {
            int id = idx + p*16384;
            float4 v = (id < 49152) ? ((const float4*)wq)[id] : ((const float4*)wp)[id - 49152];
            uint2 pk; pk.x = pack2(v.x, v.y); pk.y = pack2(v.z, v.w);
            *(uint2*)&wbf[(size_t)id*4] = pk;
        }
    }
}

// ---------------- K2: fused gn-finalize + groupnorm + QKV GEMM (BM=64, 3 blk/CU) ----------------
// Block: 64 o x 128 n, K=256 in 4 steps. Wave w: o-half (w&1), n-half (w>>1).
// LDS: Ws[2][8 chunks x 64 rows] + Hs[2][8 chunks x 128 rows] = 48 KB -> 3 blocks/CU.
__global__ __launch_bounds__(256) void qkv_fused(const float* __restrict__ x,
        const ushort_t* __restrict__ wbf, const float* __restrict__ gamma,
        const float* __restrict__ beta, const float* __restrict__ partials,
        const float* __restrict__ bias,
        ushort_t* __restrict__ qbf, ushort_t* __restrict__ kimg, ushort_t* __restrict__ vimg) {
    int b = blockIdx.z, o0 = blockIdx.y*64, n0 = blockIdx.x*128;
    int tid = threadIdx.x;
    int w = tid>>6, l = tid&63, l31 = l&31, lh = l>>5;
    int cg = tid >> 5;      // chunk 0..7 (8 c's) for H staging
    int nq = tid & 31;      // n-group of 4 for H staging
    __shared__ short Ws[2][4096];   // 512 units: [chunk 0..7][row o 0..63]
    __shared__ short Hs[2][8192];   // 1024 units: [chunk 0..7][row n 0..127]
    __shared__ float sst[16];

    if (tid < 8) {
        float s = 0.f, ss = 0.f;
        #pragma unroll
        for (int p = 0; p < 8; p++) {
            s  += partials[((b*8 + tid)*8 + p)*2];
            ss += partials[((b*8 + tid)*8 + p)*2 + 1];
        }
        const float inv = 1.f / 131072.f;
        float mu = s * inv;
        float var = fmaxf(ss * inv - mu*mu, 0.f);
        sst[tid*2]     = mu;
        sst[tid*2 + 1] = rsqrtf(var + EPSV);
    }
    __syncthreads();

    const ushort_t* wb = wbf + (size_t)o0*256;

    // W stage: 512 units, 2 per thread; wave-uniform dest base, per-lane source.
    auto stageW = [&](int bb, int c0) {
        #pragma unroll
        for (int q = 0; q < 2; q++) {
            int u0 = q*256 + w*64;          // wave-uniform unit base
            int u  = u0 + l;
            int row = u & 63, ch = u >> 6;
            gl_lds16(wb + (size_t)row*256 + c0 + ch*8, &Ws[bb][u0*8]);
        }
    };
    auto loadX = [&](int c0, float4* xv) {
        const float* xb = x + ((size_t)b*C + c0 + cg*8)*N + n0 + nq*4;
        #pragma unroll
        for (int e = 0; e < 8; e++)
            xv[e] = *(const float4*)(xb + (size_t)e*N);
    };
    auto writeH = [&](int bb, int c0, const float4* xv) {
        int cbase = c0 + cg*8;
        int g = cbase >> 5;
        float mu = sst[g*2], rs = sst[g*2+1];
        float ga[8], be[8];
        #pragma unroll
        for (int e = 0; e < 8; e++) {
            float gm = gamma[cbase+e];
            ga[e] = gm*rs;
            be[e] = beta[cbase+e] - mu*ga[e];
        }
        #pragma unroll
        for (int j = 0; j < 4; j++) {
            float h[8];
            #pragma unroll
            for (int e = 0; e < 8; e++) {
                float vx = (j==0) ? xv[e].x : (j==1) ? xv[e].y : (j==2) ? xv[e].z : xv[e].w;
                h[e] = vx*ga[e] + be[e];
            }
            uint4 pk;
            pk.x = pack2(h[0], h[1]);
            pk.y = pack2(h[2], h[3]);
            pk.z = pack2(h[4], h[5]);
            pk.w = pack2(h[6], h[7]);
            *(uint4*)&Hs[bb][(size_t)(cg*128 + nq*4 + j)*8] = pk;
        }
    };

    int wo = w & 1;          // o-half
    int wn = w >> 1;         // n-half
    f32x16 acc[2];
    #pragma unroll
    for (int nf = 0; nf < 2; nf++)
        #pragma unroll
        for (int r = 0; r < 16; r++) acc[nf][r] = 0.f;

    float4 xv[8];
    loadX(0, xv);
    stageW(0, 0);
    writeH(0, 0, xv);
    __syncthreads();

    for (int t = 0; t < 4; t++) {
        int bb = t & 1;
        if (t < 3) { stageW(bb^1, (t+1)*64); loadX((t+1)*64, xv); }
        short8 af[4];
        #pragma unroll
        for (int s = 0; s < 4; s++)
            af[s] = *(const short8*)&Ws[bb][((2*s+lh)*64 + wo*32 + l31)*8];
        #pragma unroll
        for (int nf = 0; nf < 2; nf++) {
            int nfr = wn*2 + nf;
            #pragma unroll
            for (int s = 0; s < 4; s++) {
                short8 hf = *(const short8*)&Hs[bb][((2*s+lh)*128 + nfr*32 + l31)*8];
                acc[nf] = __builtin_amdgcn_mfma_f32_32x32x16_bf16(af[s], hf, acc[nf], 0, 0, 0);
            }
        }
        if (t < 3) writeH(bb^1, (t+1)*64, xv);
        __syncthreads();
    }

    int ow = o0 + wo*32;
    float bv[16];
    #pragma unroll
    for (int r = 0; r < 16; r++) bv[r] = bias[ow + (r&3) + 8*(r>>2) + 4*lh];

    if (ow < 256) {            // ---- Q: row-major, scaled ----
        #pragma unroll
        for (int nf = 0; nf < 2; nf++) {
            int n = n0 + (wn*2 + nf)*32 + l31;
            ushort_t* row = qbf + ((size_t)(b*N + n))*256 + ow;
            #pragma unroll
            for (int rp = 0; rp < 8; rp++) {
                int r0 = rp*2;
                int cl = (r0&3) + 8*(r0>>2) + 4*lh;
                uint_t wd = cvtpk_bf16((acc[nf][r0]+bv[r0])*QSCALE, (acc[nf][r0+1]+bv[r0+1])*QSCALE);
                *(uint_t*)(row + cl) = wd;
            }
        }
    } else if (ow < 512) {     // ---- K: LDS-image blocked ----
        int cb = ow - 256;
        #pragma unroll
        for (int nf = 0; nf < 2; nf++) {
            int n = n0 + (wn*2 + nf)*32 + l31;
            ushort_t* tbase = kimg + (size_t)b*1048576 + (size_t)(n>>5)*8192
                            + (size_t)l31*8 + 4*lh;
            #pragma unroll
            for (int g = 0; g < 4; g++) {
                uint2 pk;
                pk.x = pack2(acc[nf][g*4+0]+bv[g*4+0], acc[nf][g*4+1]+bv[g*4+1]);
                pk.y = pack2(acc[nf][g*4+2]+bv[g*4+2], acc[nf][g*4+3]+bv[g*4+3]);
                *(uint2*)(tbase + (size_t)((cb>>3)+g)*256) = pk;
            }
        }
    } else {                   // ---- V: LDS-image blocked ----
        int cb = ow - 512;
        #pragma unroll
        for (int nf = 0; nf < 2; nf++) {
            int n = n0 + (wn*2 + nf)*32 + l31;
            ushort_t* tbase = vimg + (size_t)b*1048576 + (size_t)(n>>5)*8192
                            + (size_t)(l31>>3)*2048 + (l31&7);
            #pragma unroll
            for (int r = 0; r < 16; r++) {
                int cl = (r&3) + 8*(r>>2) + 4*lh;
                tbase[(size_t)(cb+cl)*8] = f2bf(acc[nf][r] + bv[r]);
            }
        }
    }
}

// ---------------- K3: MFMA flash attention, kv4, 2 blocks/CU (round-13 proven) ----------------
__global__ __launch_bounds__(256, 2) void attn_mfma(const ushort_t* __restrict__ qbf,
        const ushort_t* __restrict__ kimg, const ushort_t* __restrict__ vimg,
        ushort_t* __restrict__ part, float* __restrict__ ml) {
    int f = blockIdx.x;
    int comb = f & 15;
    int qt  = f >> 4;
    int b   = comb >> 2;
    int kvq = comb & 3;
    constexpr int NT = 32;
    int w = threadIdx.x >> 6;
    int l = threadIdx.x & 63;
    int l31 = l & 31, lh = l >> 5;

    __shared__ short KV[2][2][8192];

    int qbase = qt*128 + w*32;
    short8 qf[16];
    {
        const ushort_t* qrow = qbf + ((size_t)(b*N + qbase + l31))*256;
        #pragma unroll
        for (int s = 0; s < 16; s++)
            qf[s] = *(const short8*)(qrow + s*16 + lh*8);
    }

    f32x16 ot[8];
    #pragma unroll
    for (int mc = 0; mc < 8; mc++)
        #pragma unroll
        for (int r = 0; r < 16; r++) ot[mc][r] = 0.f;
    float m = -INFINITY, lsum = 0.f;

    const char* kbase = (const char*)kimg + (size_t)b*2097152;
    const char* vbase = (const char*)vimg + (size_t)b*2097152;

    auto stage = [&](int slot, int t) {
        int tile = kvq*32 + t;
        const char* kt = kbase + (size_t)tile*16384;
        const char* vt = vbase + (size_t)tile*16384;
        #pragma unroll
        for (int q = 0; q < 4; q++) {
            int u0 = (w*4 + q)*64;
            gl_lds16(kt + (u0 + l)*16, &KV[slot][0][u0*8]);
            gl_lds16(vt + (u0 + l)*16, &KV[slot][1][u0*8]);
        }
    };

    stage(0, 0);

    for (int t = 0; t < NT; t++) {
        int slot = t & 1;
        __syncthreads();
        if (t+1 < NT) stage(slot^1, t+1);

        f32x16 st0, st1;
        #pragma unroll
        for (int r = 0; r < 16; r++) { st0[r] = 0.f; st1[r] = 0.f; }
        const short* kb_ = &KV[slot][0][0];
        __builtin_amdgcn_s_setprio(1);
        #pragma unroll
        for (int s = 0; s < 8; s++) {
            short8 ka = *(const short8*)(kb_ + ((size_t)((4*s   + lh)*32 + l31))*8);
            short8 kc = *(const short8*)(kb_ + ((size_t)((4*s+2 + lh)*32 + l31))*8);
            st0 = __builtin_amdgcn_mfma_f32_32x32x16_bf16(ka, qf[2*s],   st0, 0, 0, 0);
            st1 = __builtin_amdgcn_mfma_f32_32x32x16_bf16(kc, qf[2*s+1], st1, 0, 0, 0);
        }
        __builtin_amdgcn_s_setprio(0);

        float sv[16];
        #pragma unroll
        for (int r = 0; r < 16; r++) sv[r] = st0[r] + st1[r];

        float a0 = fmaxf(sv[0], sv[1]),  a1 = fmaxf(sv[2], sv[3]);
        float a2 = fmaxf(sv[4], sv[5]),  a3 = fmaxf(sv[6], sv[7]);
        float a4 = fmaxf(sv[8], sv[9]),  a5 = fmaxf(sv[10], sv[11]);
        float a6 = fmaxf(sv[12], sv[13]), a7 = fmaxf(sv[14], sv[15]);
        float b0 = fmaxf(a0, a1), b1 = fmaxf(a2, a3), b2 = fmaxf(a4, a5), b3 = fmaxf(a6, a7);
        float pmax = fmaxf(fmaxf(b0, b1), fmaxf(b2, b3));
        pmax = fmaxf(pmax, __shfl_xor(pmax, 32));
        if (!__all(pmax <= m + THR2)) {
            float mn = fmaxf(m, pmax);
            float fac = fexp2(m - mn);
            m = mn;
            lsum *= fac;
            #pragma unroll
            for (int mc = 0; mc < 8; mc++)
                #pragma unroll
                for (int r = 0; r < 16; r++) ot[mc][r] *= fac;
        }
        float p[16];
        #pragma unroll
        for (int r = 0; r < 16; r++) p[r] = fexp2(sv[r] - m);
        float s0_ = (p[0]+p[1]) + (p[2]+p[3]);
        float s1_ = (p[4]+p[5]) + (p[6]+p[7]);
        float s2_ = (p[8]+p[9]) + (p[10]+p[11]);
        float s3_ = (p[12]+p[13]) + (p[14]+p[15]);
        float ls = (s0_+s1_) + (s2_+s3_);
        ls += __shfl_xor(ls, 32);
        lsum += ls;

        short8 pf0, pf1;
        {
            uint_t x0 = cvtpk_bf16(p[0], p[1]);
            uint_t y0 = cvtpk_bf16(p[4], p[5]);
            uint_t x1 = cvtpk_bf16(p[2], p[3]);
            uint_t y1 = cvtpk_bf16(p[6], p[7]);
            auto r0 = __builtin_amdgcn_permlane32_swap(x0, y0, false, false);
            auto r1 = __builtin_amdgcn_permlane32_swap(x1, y1, false, false);
            union { uint_t u[4]; short8 s8; } u_;
            u_.u[0] = r0[0]; u_.u[1] = r1[0]; u_.u[2] = r0[1]; u_.u[3] = r1[1];
            pf0 = u_.s8;
            uint_t x2 = cvtpk_bf16(p[8],  p[9]);
            uint_t y2 = cvtpk_bf16(p[12], p[13]);
            uint_t x3 = cvtpk_bf16(p[10], p[11]);
            uint_t y3 = cvtpk_bf16(p[14], p[15]);
            auto r2 = __builtin_amdgcn_permlane32_swap(x2, y2, false, false);
            auto r3 = __builtin_amdgcn_permlane32_swap(x3, y3, false, false);
            union { uint_t u[4]; short8 s8; } u2_;
            u2_.u[0] = r2[0]; u2_.u[1] = r3[0]; u2_.u[2] = r2[1]; u2_.u[3] = r3[1];
            pf1 = u2_.s8;
        }

        const short* vb_ = &KV[slot][1][0];
        __builtin_amdgcn_s_setprio(1);
        #pragma unroll
        for (int mc = 0; mc < 8; mc++) {
            short8 v0 = *(const short8*)(vb_ + ((size_t)((lh)*256   + mc*32 + l31))*8);
            short8 v1 = *(const short8*)(vb_ + ((size_t)((2+lh)*256 + mc*32 + l31))*8);
            ot[mc] = __builtin_amdgcn_mfma_f32_32x32x16_bf16(v0, pf0, ot[mc], 0, 0, 0);
            ot[mc] = __builtin_amdgcn_mfma_f32_32x32x16_bf16(v1, pf1, ot[mc], 0, 0, 0);
        }
        __builtin_amdgcn_s_setprio(0);
    }

    float invl = 1.f / lsum;
    ushort_t* pbase = part + (size_t)kvq*4194304 + ((size_t)(b*N + qbase + l31))*256;
    #pragma unroll
    for (int mc = 0; mc < 8; mc++)
        #pragma unroll
        for (int rp = 0; rp < 8; rp++) {
            int r0 = rp*2;
            uint_t wd = cvtpk_bf16(ot[mc][r0]*invl, ot[mc][r0+1]*invl);
            int c0 = (r0 & 3) + 8*(r0 >> 2) + 4*lh + 32*mc;
            *(uint_t*)(pbase + c0) = wd;
        }
    if (l < 32) {
        size_t row = (size_t)kvq*16384 + b*4096 + qbase + l;
        ml[row*2]     = m;
        ml[row*2 + 1] = lsum;
    }
}

// ---------------- K4: proj GEMM + inline 4-way merge + bias + residual ----------------
__global__ __launch_bounds__(256) void proj_merge(const ushort_t* __restrict__ part,
        const float* __restrict__ ml, const ushort_t* __restrict__ wpbf,
        const float* __restrict__ bp, const float* __restrict__ x, float* __restrict__ out) {
    int b = blockIdx.z, o0 = blockIdx.y*128, n0 = blockIdx.x*64;
    int tid = threadIdx.x;
    int w = tid>>6, l = tid&63, l31 = l&31, lh = l>>5;
    __shared__ short Ws[2][8192];
    __shared__ short Hs[2][4096];

    const ushort_t* wb = wpbf + (size_t)o0*256;

    int srow = tid & 63;
    int ch0  = tid >> 6;
    size_t rowbase = ((size_t)(b*4096 + n0 + srow))*256;
    float wv[4];
    {
        float mv[4], lv[4];
        #pragma unroll
        for (int i = 0; i < 4; i++) {
            size_t rr = (size_t)i*16384 + b*4096 + n0 + srow;
            mv[i] = ml[rr*2];
            lv[i] = ml[rr*2 + 1];
        }
        float M = fmaxf(fmaxf(mv[0], mv[1]), fmaxf(mv[2], mv[3]));
        float wsum = 0.f;
        #pragma unroll
        for (int i = 0; i < 4; i++) { wv[i] = fexp2(mv[i] - M)*lv[i]; wsum += wv[i]; }
        float inv = 1.f / wsum;
        #pragma unroll
        for (int i = 0; i < 4; i++) wv[i] *= inv;
    }

    auto stageW = [&](int bb, int c0) {
        #pragma unroll
        for (int q = 0; q < 4; q++) {
            int u0 = (q*4 + w)*64;
            int u  = u0 + l;
            int row = u & 127, ch = u >> 7;
            gl_lds16(wb + (size_t)row*256 + c0 + ch*8, &Ws[bb][u0*8]);
        }
    };
    short8 hA[4], hB[4];
    auto Hload = [&](int c0) {
        #pragma unroll
        for (int i = 0; i < 4; i++) {
            const ushort_t* pp = part + (size_t)i*4194304 + rowbase + c0;
            hA[i] = *(const short8*)(pp + ch0*8);
            hB[i] = *(const short8*)(pp + (ch0+4)*8);
        }
    };
    auto Hwrite = [&](int bb) {
        float oA[8], oB[8];
        #pragma unroll
        for (int e = 0; e < 8; e++) { oA[e] = 0.f; oB[e] = 0.f; }
        #pragma unroll
        for (int i = 0; i < 4; i++) {
            float wi = wv[i];
            #pragma unroll
            for (int e = 0; e < 8; e++) {
                oA[e] += wi*bf2f((ushort_t)hA[i][e]);
                oB[e] += wi*bf2f((ushort_t)hB[i][e]);
            }
        }
        uint4 pkA, pkB;
        pkA.x = pack2(oA[0], oA[1]); pkA.y = pack2(oA[2], oA[3]);
        pkA.z = pack2(oA[4], oA[5]); pkA.w = pack2(oA[6], oA[7]);
        pkB.x = pack2(oB[0], oB[1]); pkB.y = pack2(oB[2], oB[3]);
        pkB.z = pack2(oB[4], oB[5]); pkB.w = pack2(oB[6], oB[7]);
        *(uint4*)&Hs[bb][(size_t)(ch0*64 + srow)*8]     = pkA;
        *(uint4*)&Hs[bb][(size_t)((ch0+4)*64 + srow)*8] = pkB;
    };

    f32x16 acc[2];
    #pragma unroll
    for (int nf = 0; nf < 2; nf++)
        #pragma unroll
        for (int r = 0; r < 16; r++) acc[nf][r] = 0.f;

    stageW(0, 0);
    Hload(0);
    Hwrite(0);
    __syncthreads();
    for (int t = 0; t < 4; t++) {
        int bb = t & 1;
        if (t < 3) { stageW(bb^1, (t+1)*64); Hload((t+1)*64); }
        short8 af[4];
        #pragma unroll
        for (int s = 0; s < 4; s++)
            af[s] = *(const short8*)&Ws[bb][((2*s+lh)*128 + w*32 + l31)*8];
        #pragma unroll
        for (int nf = 0; nf < 2; nf++) {
            #pragma unroll
            for (int s = 0; s < 4; s++) {
                short8 hf = *(const short8*)&Hs[bb][((2*s+lh)*64 + nf*32 + l31)*8];
                acc[nf] = __builtin_amdgcn_mfma_f32_32x32x16_bf16(af[s], hf, acc[nf], 0, 0, 0);
            }
        }
        if (t < 3) Hwrite(bb^1);
        __syncthreads();
    }

    int cw = o0 + w*32;
    float bv[16];
    #pragma unroll
    for (int r = 0; r < 16; r++) bv[r] = bp[cw + (r&3) + 8*(r>>2) + 4*lh];

    #pragma unroll
    for (int nf = 0; nf < 2; nf++) {
        int n = n0 + nf*32 + l31;
        #pragma unroll
        for (int r = 0; r < 16; r++) {
            int cl = (r&3) + 8*(r>>2) + 4*lh;
            size_t a = ((size_t)b*C + cw + cl)*N + n;
            out[a] = acc[nf][r] + bv[r] + x[a];
        }
    }
}

extern "C" void kernel_launch(void* const* d_in, const int* in_sizes, int n_in,
                              void* d_out, int out_size, void* d_ws, size_t ws_size,
                              hipStream_t stream) {
    const float* x      = (const float*)d_in[0];
    const float* gamma  = (const float*)d_in[1];
    const float* beta   = (const float*)d_in[2];
    const float* w_qkv  = (const float*)d_in[3];
    const float* b_qkv  = (const float*)d_in[4];
    const float* w_proj = (const float*)d_in[5];
    const float* b_proj = (const float*)d_in[6];
    float* out = (float*)d_out;
    char* wsb  = (char*)d_ws;

    const size_t MB = 1048576;
    ushort_t* qbf  = (ushort_t*)(wsb);                       // 8 MB
    ushort_t* kimg = (ushort_t*)(wsb + 8*MB);                // 8 MB
    ushort_t* vimg = (ushort_t*)(wsb + 16*MB);               // 8 MB
    ushort_t* part = (ushort_t*)(wsb + 24*MB);               // 32 MB (4 quarters)
    float*    ml   = (float*)  (wsb + 56*MB);                // 512 KB
    float* partials = (float*) (wsb + 56*MB + 524288);       // 2 KB
    ushort_t* wbf  = (ushort_t*)(wsb + 56*MB + 528384);      // 512 KB

    gn_wconv<<<dim3(320), dim3(256), 0, stream>>>(x, partials, w_qkv, w_proj, wbf);
    qkv_fused<<<dim3(32, 12, 4), dim3(256), 0, stream>>>(x, wbf, gamma, beta, partials, b_qkv, qbf, kimg, vimg);
    attn_mfma<<<dim3(512), dim3(256), 0, stream>>>(qbf, kimg, vimg, part, ml);
    proj_merge<<<dim3(64, 2, 4), dim3(256), 0, stream>>>(part, ml, wbf + 196608, b_proj, x, out);
}